// Round 3
// baseline (148.861 us; speedup 1.0000x reference)
//
#include <hip/hip_runtime.h>
#include <math.h>

// B=2, H=8, L=2048, E=512, d=64
constexpr int CL = 2048;
constexpr int NROW = 32768;
constexpr float SCALE = 1.0f / 2048.0f;
constexpr float TWO_PI = 6.283185307179586f;

typedef short short8 __attribute__((ext_vector_type(8)));
typedef float floatx4 __attribute__((ext_vector_type(4)));
typedef _Float16 half8 __attribute__((ext_vector_type(8)));
typedef __fp16 fp16x2 __attribute__((ext_vector_type(2)));   // cvt_pkrtz return type

__device__ inline unsigned short f2bf(float f) {
  union { float f; unsigned u; } c; c.f = f;
  unsigned u = c.u + 0x7FFF + ((c.u >> 16) & 1);
  return (unsigned short)(u >> 16);
}
__device__ inline float bf2f(unsigned short h) {
  union { unsigned u; float f; } c; c.u = ((unsigned)h) << 16;
  return c.f;
}
__device__ inline unsigned short f2h(float f) {
  union { _Float16 h; unsigned short u; } c; c.h = (_Float16)f; return c.u;
}
__device__ inline float h2f(unsigned short u) {
  union { unsigned short u; _Float16 h; } c; c.u = u; return (float)c.h;
}
// XOR swizzle for [rows][64 ushort] LDS tiles: 16B-group g at row r -> g^(r&7).
__device__ inline int sw(int r, int o) {
  return r * 64 + ((((o >> 3) ^ r) & 7) << 3) + (o & 7);
}

// ---------------- workspace ----------------
constexpr size_t F_C0S = 0;
constexpr size_t F_C0Z = F_C0S + NROW;
constexpr size_t F_END = F_C0Z + NROW;
constexpr size_t U_CH  = 0;
constexpr size_t U_CL  = U_CH + (size_t)NROW * 64;
constexpr size_t U_BF  = U_CL + (size_t)NROW * 64;
constexpr size_t U_VF  = U_BF + (size_t)2 * 131072;
constexpr size_t U_END = U_VF + (size_t)2097152;   // Vf = 16bh * 32st * 8frag * 512
// f32 partial plane for k4 split-K (z=1 chunk), appended after ushort region.

// ================================================================ mega launch 1
// blocks [0,64):   Bf basis-fragment table (fp16, single plane)
// blocks [64,576): kv V-fragment build (fp16, single plane)
// blocks [576,1088): fused DFT+coef (DFT in bf16-split, coefs emitted fp16 hi/lo)
__launch_bounds__(256)
__global__ void mega1(const float* __restrict__ q, const float* __restrict__ kin,
                      const float* __restrict__ values,
                      unsigned short* __restrict__ Bf, unsigned short* __restrict__ Vf,
                      unsigned short* __restrict__ Ch, unsigned short* __restrict__ Cl,
                      float* __restrict__ c0s) {
  __shared__ char smem[16896];
  int tid = threadIdx.x;
  int blk = blockIdx.x;
  if (blk < 64) {
    int gid = blk * 256 + tid;
    int lt = gid >> 7, rem = gid & 127, ks = rem >> 6, lane = rem & 63;
    int qd = lane >> 4, n = lane & 15;
    int t = lt * 16 + n;
    size_t base = ((size_t)((lt * 2 + ks) * 64 + lane)) * 8;
    for (int j = 0; j < 8; ++j) {
      int kr = ks * 32 + qd * 8 + j;
      int freq = (kr < 32) ? (kr + 1) : (kr - 31);
      int ph = (freq * t) & (CL - 1);
      float ang = (float)ph * (TWO_PI / (float)CL);
      float val = (kr < 32) ? cosf(ang) : sinf(ang);
      Bf[base + j] = f2h(val);
    }
    return;
  }
  if (blk < 576) {
    // V tile [64 s][64 d] -> B-operand frags (fp16): frag = dt*2+ksp;
    // elem[lane*8+j] = V[s = ksp*32 + qd*8 + j][d = dt*16 + n]
    float* Vt = (float*)smem;                    // [64][65]
    int idx = blk - 64;
    int bh = idx >> 5, st = idx & 31;
    int b = bh >> 3, h = bh & 7;
    {
      int sl = tid >> 2, dq = (tid & 3) * 16;
      const float4* src = (const float4*)(values + ((size_t)(b * 2048 + st * 64 + sl)) * 512 + h * 64 + dq);
#pragma unroll
      for (int m = 0; m < 4; ++m) {
        float4 t4 = src[m];
        int base = sl * 65 + dq + m * 4;
        Vt[base] = t4.x; Vt[base + 1] = t4.y; Vt[base + 2] = t4.z; Vt[base + 3] = t4.w;
      }
    }
    __syncthreads();
#pragma unroll
    for (int iter = 0; iter < 2; ++iter) {
      int it = iter * 256 + tid;
      int lane = it & 63, ksp = (it >> 6) & 1, dt = it >> 7;
      int qd = lane >> 4, n = lane & 15;
      int d = dt * 16 + n;
      short8 hi;
#pragma unroll
      for (int j = 0; j < 8; ++j)
        hi[j] = (short)f2h(Vt[(ksp * 32 + qd * 8 + j) * 65 + d]);
      size_t off = (((size_t)(bh * 32 + st)) * 8 + dt * 2 + ksp) * 512 + lane * 8;
      *(short8*)(Vf + off) = hi;
    }
    return;
  }
  // ---- fused DFT + coef. Block = 8 s x 8 h of one b (64 rows).
  // Tws has only 64 distinct (cos,sin) pairs: build a 64-entry LDS table with
  // ONE sincosf per lane (bit-identical inputs -> bit-identical table), then
  // fill the 2048-entry bf16-split planes by lookup (was: 8 sincosf/thread).
  unsigned short* Tws = (unsigned short*)smem;   // 4 planes x 2048 (bf16 split)
  float* tab = (float*)(smem + 16384);           // 64 x {cos, sin}
  if (tid < 64) {
    float ang = (float)tid * (TWO_PI / 64.0f);
    float s1, c1;
    sincosf(ang, &s1, &c1);
    tab[tid * 2] = c1; tab[tid * 2 + 1] = s1;
  }
  __syncthreads();
  {
    int g0 = tid * 8;
    int lane_g = (g0 >> 3) & 63, ksp_g = (g0 >> 9) & 1, ct_g = g0 >> 10;
    int f = ct_g * 16 + (lane_g & 15);
    int cb = ksp_g * 32 + ((lane_g >> 4) & 3) * 8;
#pragma unroll
    for (int j = 0; j < 8; ++j) {
      int kk = (f * (cb + j)) & 63;
      float re = tab[kk * 2], im = -tab[kk * 2 + 1];
      unsigned short rh = f2bf(re), ih = f2bf(im);
      Tws[g0 + j] = rh;        Tws[2048 + g0 + j] = f2bf(re - bf2f(rh));
      Tws[4096 + g0 + j] = ih; Tws[6144 + g0 + j] = f2bf(im - bf2f(ih));
    }
  }
  __syncthreads();
  int w = tid >> 6, lane = tid & 63, qd = lane >> 4, n = lane & 15;
  int blk1 = blk - 576;
  int b = blk1 >> 8, s0 = (blk1 & 255) * 8;
  int sA = s0 + w * 2 + (n >> 3), hA = n & 7;
  const float* qp = q + ((size_t)(b * 2048 + sA)) * 512 + hA * 64 + qd * 8;
  const float* kp = kin + ((size_t)(b * 2048 + sA)) * 512 + hA * 64 + qd * 8;
  float qv[16], kv[16];
#pragma unroll
  for (int ksp = 0; ksp < 2; ++ksp) {
    float4 a0 = *(const float4*)(qp + ksp * 32);
    float4 a1 = *(const float4*)(qp + ksp * 32 + 4);
    float4 b0 = *(const float4*)(kp + ksp * 32);
    float4 b1 = *(const float4*)(kp + ksp * 32 + 4);
    qv[ksp*8+0]=a0.x; qv[ksp*8+1]=a0.y; qv[ksp*8+2]=a0.z; qv[ksp*8+3]=a0.w;
    qv[ksp*8+4]=a1.x; qv[ksp*8+5]=a1.y; qv[ksp*8+6]=a1.z; qv[ksp*8+7]=a1.w;
    kv[ksp*8+0]=b0.x; kv[ksp*8+1]=b0.y; kv[ksp*8+2]=b0.z; kv[ksp*8+3]=b0.w;
    kv[ksp*8+4]=b1.x; kv[ksp*8+5]=b1.y; kv[ksp*8+6]=b1.z; kv[ksp*8+7]=b1.w;
  }
  float aq = 0.0f, ak = 0.0f;
#pragma unroll
  for (int i = 0; i < 16; ++i) {
    float sg = (i & 1) ? -1.0f : 1.0f;
    aq += sg * qv[i]; ak += sg * kv[i];
  }
  aq += __shfl_xor(aq, 16); aq += __shfl_xor(aq, 32);
  ak += __shfl_xor(ak, 16); ak += __shfl_xor(ak, 32);
  short8 Aqh[2], Aql[2], Akh[2], Akl[2];
#pragma unroll
  for (int ksp = 0; ksp < 2; ++ksp) {
#pragma unroll
    for (int j = 0; j < 8; ++j) {
      unsigned short hq = f2bf(qv[ksp*8+j]);
      Aqh[ksp][j] = (short)hq; Aql[ksp][j] = (short)f2bf(qv[ksp*8+j] - bf2f(hq));
      unsigned short hk = f2bf(kv[ksp*8+j]);
      Akh[ksp][j] = (short)hk; Akl[ksp][j] = (short)f2bf(kv[ksp*8+j] - bf2f(hk));
    }
  }
  float lmr[4] = {0,0,0,0};
  float c0v[4] = {0,0,0,0};
  int hC = (qd * 4) & 7;
  int sC = s0 + w * 2 + (qd >> 1);
#pragma unroll
  for (int ct = 0; ct < 2; ++ct) {
    short8 Brh[2], Brl[2], Bih[2], Bil[2];
#pragma unroll
    for (int ksp = 0; ksp < 2; ++ksp) {
      size_t off = (size_t)ct * 1024 + ksp * 512 + lane * 8;
      Brh[ksp] = *(const short8*)(Tws + off);
      Brl[ksp] = *(const short8*)(Tws + 2048 + off);
      Bih[ksp] = *(const short8*)(Tws + 4096 + off);
      Bil[ksp] = *(const short8*)(Tws + 6144 + off);
    }
    floatx4 qre = {0,0,0,0}, qim = {0,0,0,0}, kre = {0,0,0,0}, kim = {0,0,0,0};
#pragma unroll
    for (int ksp = 0; ksp < 2; ++ksp) {
      qre = __builtin_amdgcn_mfma_f32_16x16x32_bf16(Aqh[ksp], Brh[ksp], qre, 0,0,0);
      qre = __builtin_amdgcn_mfma_f32_16x16x32_bf16(Aqh[ksp], Brl[ksp], qre, 0,0,0);
      qre = __builtin_amdgcn_mfma_f32_16x16x32_bf16(Aql[ksp], Brh[ksp], qre, 0,0,0);
      qim = __builtin_amdgcn_mfma_f32_16x16x32_bf16(Aqh[ksp], Bih[ksp], qim, 0,0,0);
      qim = __builtin_amdgcn_mfma_f32_16x16x32_bf16(Aqh[ksp], Bil[ksp], qim, 0,0,0);
      qim = __builtin_amdgcn_mfma_f32_16x16x32_bf16(Aql[ksp], Bih[ksp], qim, 0,0,0);
      kre = __builtin_amdgcn_mfma_f32_16x16x32_bf16(Akh[ksp], Brh[ksp], kre, 0,0,0);
      kre = __builtin_amdgcn_mfma_f32_16x16x32_bf16(Akh[ksp], Brl[ksp], kre, 0,0,0);
      kre = __builtin_amdgcn_mfma_f32_16x16x32_bf16(Akl[ksp], Brh[ksp], kre, 0,0,0);
      kim = __builtin_amdgcn_mfma_f32_16x16x32_bf16(Akh[ksp], Bih[ksp], kim, 0,0,0);
      kim = __builtin_amdgcn_mfma_f32_16x16x32_bf16(Akh[ksp], Bil[ksp], kim, 0,0,0);
      kim = __builtin_amdgcn_mfma_f32_16x16x32_bf16(Akl[ksp], Bih[ksp], kim, 0,0,0);
    }
    float xre[4], xim[4], tre = 0, tim = 0;
#pragma unroll
    for (int r = 0; r < 4; ++r) {
      xre[r] = qre[r] * kre[r] + qim[r] * kim[r];
      xim[r] = qim[r] * kre[r] - qre[r] * kim[r];
      tre += xre[r]; tim += xim[r];
    }
    tre += __shfl_xor(tre, 16);
    tim += __shfl_xor(tim, 16);
    float mre = tre * 0.125f, mim = tim * 0.125f;
#pragma unroll
    for (int r = 0; r < 4; ++r) {
      float yre = xre[r] - mre, yim = xim[r] - mim;
      if (ct == 0 && n == 0) {
        c0v[r] = yre * SCALE;
      } else {
        int f = ct * 16 + n;
        float a = 2.0f * yre * SCALE, bb = -2.0f * yim * SCALE;
        size_t rowid = (size_t)((b * 8 + hC + r) * 2048 + sC);
        unsigned short ah = f2h(a);
        Ch[rowid * 64 + f - 1] = ah;
        Cl[rowid * 64 + f - 1] = f2h(a - h2f(ah));
        unsigned short bh2 = f2h(bb);
        Ch[rowid * 64 + 32 + f - 1] = bh2;
        Cl[rowid * 64 + 32 + f - 1] = f2h(bb - h2f(bh2));
        lmr[r] += fabsf(a) + fabsf(bb);
      }
    }
  }
  float X32 = aq * ak;
  float m32 = X32;
  m32 += __shfl_xor(m32, 1); m32 += __shfl_xor(m32, 2); m32 += __shfl_xor(m32, 4);
  float A32 = 2.0f * (X32 - m32 * 0.125f) * SCALE;
  if (qd == 0) {
    size_t rowid = (size_t)((b * 8 + (n & 7)) * 2048 + s0 + w * 2 + (n >> 3));
    unsigned short ah = f2h(A32);
    Ch[rowid * 64 + 31] = ah;
    Cl[rowid * 64 + 31] = f2h(A32 - h2f(ah));
    Ch[rowid * 64 + 63] = 0;
    Cl[rowid * 64 + 63] = 0;
  }
  float absA32 = fabsf(A32);
#pragma unroll
  for (int r = 0; r < 4; ++r) {
    lmr[r] += __shfl_xor(lmr[r], 1);
    lmr[r] += __shfl_xor(lmr[r], 2);
    lmr[r] += __shfl_xor(lmr[r], 4);
    lmr[r] += __shfl_xor(lmr[r], 8);
  }
  int qb = lane & 48;
#pragma unroll
  for (int r = 0; r < 4; ++r) {
    float a32r = __shfl(absA32, qb + (qb >> 2) + r);
    if (n == 0) {
      float M = fabsf(c0v[r]) + lmr[r] + a32r;
      size_t rowid = (size_t)((b * 8 + hC + r) * 2048 + sC);
      c0s[rowid] = c0v[r] - M;
    }
  }
}

// ---------------------------------------------------------------- k3: c0z = c0 - log(Z)
// fp16 logit GEMM: 4 MFMA per (c, lt). 512 threads / 8 waves per block.
// UNCHANGED this round (will surface in top-5 counters once k4 drops).
__launch_bounds__(512)
__global__ void k3_z(const unsigned short* __restrict__ Ch, const unsigned short* __restrict__ Cl,
                     const float* __restrict__ c0s, const unsigned short* __restrict__ Bf,
                     float* __restrict__ c0z) {
  __shared__ float Zl[64];
  int tid = threadIdx.x;
  int w = tid >> 6, lane = tid & 63, q = lane >> 4, n = lane & 15;
  int rowbase = blockIdx.x * 64;
  half8 Ah[4][2], Al[4][2];
#pragma unroll
  for (int c = 0; c < 4; ++c)
#pragma unroll
    for (int ksp = 0; ksp < 2; ++ksp) {
      size_t srow = (size_t)(rowbase + c * 16 + n);
      Ah[c][ksp] = *(const half8*)(Ch + srow * 64 + ksp * 32 + q * 8);
      Al[c][ksp] = *(const half8*)(Cl + srow * 64 + ksp * 32 + q * 8);
    }
  float c0r[4][4], zacc[4][4];
#pragma unroll
  for (int c = 0; c < 4; ++c)
#pragma unroll
    for (int r = 0; r < 4; ++r) {
      c0r[c][r] = c0s[rowbase + c * 16 + q * 4 + r];
      zacc[c][r] = 0.0f;
    }
  if (tid < 64) Zl[tid] = 0.0f;
  for (int lt = w; lt < 128; lt += 8) {
    size_t b0 = ((size_t)(lt * 2 + 0) * 64 + lane) * 8;
    size_t b1 = ((size_t)(lt * 2 + 1) * 64 + lane) * 8;
    half8 Bh0 = *(const half8*)(Bf + b0);
    half8 Bh1 = *(const half8*)(Bf + b1);
#pragma unroll
    for (int c = 0; c < 4; ++c) {
      floatx4 y = {0.f, 0.f, 0.f, 0.f};
      y = __builtin_amdgcn_mfma_f32_16x16x32_f16(Ah[c][0], Bh0, y, 0, 0, 0);
      y = __builtin_amdgcn_mfma_f32_16x16x32_f16(Ah[c][1], Bh1, y, 0, 0, 0);
      y = __builtin_amdgcn_mfma_f32_16x16x32_f16(Al[c][0], Bh0, y, 0, 0, 0);
      y = __builtin_amdgcn_mfma_f32_16x16x32_f16(Al[c][1], Bh1, y, 0, 0, 0);
#pragma unroll
      for (int r = 0; r < 4; ++r) zacc[c][r] += __expf(y[r] + c0r[c][r]);
    }
  }
  __syncthreads();
#pragma unroll
  for (int c = 0; c < 4; ++c)
#pragma unroll
    for (int r = 0; r < 4; ++r) {
#pragma unroll
      for (int m = 1; m < 16; m <<= 1) zacc[c][r] += __shfl_xor(zacc[c][r], m, 16);
      if (n == 0) atomicAdd(&Zl[c * 16 + q * 4 + r], zacc[c][r]);
    }
  __syncthreads();
  if (tid < 64) c0z[rowbase + tid] = c0s[rowbase + tid] - __logf(Zl[tid]);
}

// ---------------------------------------------------------------- k4: output
// R9 skeleton (64-l blocks, cross-barrier PV pipeline), fp16 everywhere.
// s-dim split-K (gridDim.z=2), disjoint-plane partials + k5_add combine.
// NEW (R3): counted-wait barrier. __syncthreads() forced
// `s_waitcnt vmcnt(0) lgkmcnt(0)` -> global A/V prefetch latency drained on
// the critical path EVERY tile (why R2's 2x occupancy bought 0 us). Only the
// Es LDS traffic needs barrier ordering (A/V go to private regs), so wait on
// lgkmcnt(0) only; vmcnt waits happen at first use, a full tile later.
#define K4_BARRIER()                                     \
  do {                                                   \
    asm volatile("s_waitcnt lgkmcnt(0)" ::: "memory");   \
    __builtin_amdgcn_sched_barrier(0);                   \
    __builtin_amdgcn_s_barrier();                        \
  } while (0)

#define K4_LOADA(st_, sl_)                                                           \
  do {                                                                               \
    int rz_ = bh * 2048 + (st_) * 64;                                                \
    size_t srow_ = (size_t)(rz_ + w * 16 + n);                                       \
    Ahs[sl_][0] = *(const half8*)(Ch + srow_ * 64 + qd * 8);                         \
    Ahs[sl_][1] = *(const half8*)(Ch + srow_ * 64 + 32 + qd * 8);                    \
    Als[sl_][0] = *(const half8*)(Cl + srow_ * 64 + qd * 8);                         \
    Als[sl_][1] = *(const half8*)(Cl + srow_ * 64 + 32 + qd * 8);                    \
    c0rs[sl_] = *(const float4*)(c0z + rz_ + w * 16 + qd * 4);                       \
  } while (0)

#define K4_LOADV(st_, sl_)                                                           \
  do {                                                                               \
    size_t vo_ = (((size_t)(bh * 32 + (st_))) * 8 + w * 2) * 512 + lane * 8;         \
    Vhs[sl_][0] = *(const half8*)(Vf + vo_);                                         \
    Vhs[sl_][1] = *(const half8*)(Vf + vo_ + 512);                                   \
  } while (0)

#define K4_PV(sl_)                                                                   \
  do {                                                                               \
    _Pragma("unroll")                                                                \
    for (int ksp_ = 0; ksp_ < 2; ++ksp_) {                                           \
      half8 Vh_ = Vhs[sl_][ksp_];                                                    \
      _Pragma("unroll")                                                              \
      for (int lt_ = 0; lt_ < 4; ++lt_) {                                            \
        half8 E_ = *(const half8*)(&Es[sl_][sw(lt_ * 16 + n, ksp_ * 32 + qd * 8)]);  \
        accv[lt_] = __builtin_amdgcn_mfma_f32_16x16x32_f16(E_, Vh_, accv[lt_],0,0,0);\
      }                                                                              \
    }                                                                                \
  } while (0)

#define K4_ITER(st_, sl_, first_, last_)                                             \
  do {                                                                               \
    float4 cc_ = c0rs[sl_];                                                          \
    _Pragma("unroll")                                                                \
    for (int lt_ = 0; lt_ < 4; ++lt_) {                                              \
      floatx4 y = {0, 0, 0, 0};                                                      \
      y = __builtin_amdgcn_mfma_f32_16x16x32_f16(Ahs[sl_][0], Bbh[lt_][0], y,0,0,0); \
      y = __builtin_amdgcn_mfma_f32_16x16x32_f16(Ahs[sl_][1], Bbh[lt_][1], y,0,0,0); \
      y = __builtin_amdgcn_mfma_f32_16x16x32_f16(Als[sl_][0], Bbh[lt_][0], y,0,0,0); \
      y = __builtin_amdgcn_mfma_f32_16x16x32_f16(Als[sl_][1], Bbh[lt_][1], y,0,0,0); \
      union { fp16x2 h; unsigned u; } pk0_, pk1_;                                    \
      pk0_.h = __builtin_amdgcn_cvt_pkrtz(__expf(y[0] + cc_.x), __expf(y[1] + cc_.y));\
      pk1_.h = __builtin_amdgcn_cvt_pkrtz(__expf(y[2] + cc_.z), __expf(y[3] + cc_.w));\
      uint2 p_;                                                                      \
      p_.x = pk0_.u; p_.y = pk1_.u;                                                  \
      *(uint2*)(&Es[sl_][sw(lt_ * 16 + n, w * 16 + qd * 4)]) = p_;                   \
    }                                                                                \
    if (!(last_)) { K4_LOADA((st_) + 1, 1 - (sl_)); }                                \
    if (!(first_)) { K4_PV(1 - (sl_)); }                                             \
    if (!(last_)) { K4_LOADV((st_) + 1, 1 - (sl_)); }                                \
    K4_BARRIER();                                                                    \
  } while (0)

__launch_bounds__(256, 4)
__global__ void k4_out(const unsigned short* __restrict__ Ch, const unsigned short* __restrict__ Cl,
                       const float* __restrict__ c0z, const unsigned short* __restrict__ Bf,
                       const unsigned short* __restrict__ Vf, float* __restrict__ out,
                       float* __restrict__ P1) {
  __shared__ unsigned short Es[2][64 * 64];
  int tid = threadIdx.x;
  int w = tid >> 6, lane = tid & 63, qd = lane >> 4, n = lane & 15;
  int bh = blockIdx.x, b = bh >> 3, h = bh & 7;
  int l0 = blockIdx.y * 64, lt0 = blockIdx.y * 4;
  int st0 = blockIdx.z * 16;                      // s-chunk: 16 tiles of 64 s each
  float* dst = (blockIdx.z == 0) ? out : P1;
  half8 Bbh[4][2];
#pragma unroll
  for (int lt = 0; lt < 4; ++lt)
#pragma unroll
    for (int ksp = 0; ksp < 2; ++ksp) {
      size_t bo = ((size_t)((lt0 + lt) * 2 + ksp) * 64 + lane) * 8;
      Bbh[lt][ksp] = *(const half8*)(Bf + bo);
    }
  floatx4 accv[4];
#pragma unroll
  for (int lt = 0; lt < 4; ++lt) accv[lt] = (floatx4){0.f, 0.f, 0.f, 0.f};
  half8 Ahs[2][2], Als[2][2], Vhs[2][2];
  float4 c0rs[2];
  K4_LOADA(st0, 0);
  K4_LOADV(st0, 0);
  K4_ITER(st0, 0, true, false);
  for (int st2 = 0; st2 < 7; ++st2) {
    K4_ITER(st0 + 2 * st2 + 1, 1, false, false);
    K4_ITER(st0 + 2 * st2 + 2, 0, false, false);
  }
  K4_ITER(st0 + 15, 1, false, true);
  K4_PV(1);   // drain: PV of last tile of this chunk (Es[1], V slot 1)
  // Store partial: accv[lt]: d = w*16 + n ; l = l0 + lt*16 + qd*4 + r ; [b][d][h][l]
#pragma unroll
  for (int lt = 0; lt < 4; ++lt) {
    size_t base = ((size_t)((b * 64 + w * 16 + n) * 8 + h)) * 2048 + l0 + lt * 16 + qd * 4;
    float4 o4;
    o4.x = accv[lt][0]; o4.y = accv[lt][1]; o4.z = accv[lt][2]; o4.w = accv[lt][3];
    *(float4*)(dst + base) = o4;
  }
}

// ---------------------------------------------------------------- k5: out += P1
__launch_bounds__(256)
__global__ void k5_add(float* __restrict__ out, const float* __restrict__ P1) {
  size_t i = ((size_t)blockIdx.x * 256 + threadIdx.x) * 4;
  float4 a = *(const float4*)(out + i);
  float4 b = *(const float4*)(P1 + i);
  a.x += b.x; a.y += b.y; a.z += b.z; a.w += b.w;
  *(float4*)(out + i) = a;
}

extern "C" void kernel_launch(void* const* d_in, const int* in_sizes, int n_in,
                              void* d_out, int out_size, void* d_ws, size_t ws_size,
                              hipStream_t stream) {
  const float* q = (const float*)d_in[0];
  const float* k = (const float*)d_in[1];
  const float* v = (const float*)d_in[2];
  float* out = (float*)d_out;
  float* ws = (float*)d_ws;
  float* c0s = ws + F_C0S;
  float* c0z = ws + F_C0Z;
  unsigned short* ubase = (unsigned short*)(ws + F_END);
  unsigned short* Ch = ubase + U_CH;
  unsigned short* Cl = ubase + U_CL;
  unsigned short* Bf = ubase + U_BF;
  unsigned short* Vf = ubase + U_VF;
  float* P1 = (float*)(ubase + U_END);   // 2M f32 partial plane (16B-aligned)

  mega1<<<dim3(1088), dim3(256), 0, stream>>>(q, k, v, Bf, Vf, Ch, Cl, c0s);
  k3_z<<<dim3(512), dim3(512), 0, stream>>>(Ch, Cl, c0s, Bf, c0z);
  k4_out<<<dim3(16, 32, 2), dim3(256), 0, stream>>>(Ch, Cl, c0z, Bf, Vf, out, P1);
  k5_add<<<dim3(2048), dim3(256), 0, stream>>>(out, P1);
}

// Round 4
// 147.444 us; speedup vs baseline: 1.0096x; 1.0096x over previous
//
#include <hip/hip_runtime.h>
#include <math.h>

// B=2, H=8, L=2048, E=512, d=64
constexpr int CL = 2048;
constexpr int NROW = 32768;
constexpr float SCALE = 1.0f / 2048.0f;
constexpr float TWO_PI = 6.283185307179586f;

typedef short short8 __attribute__((ext_vector_type(8)));
typedef float floatx4 __attribute__((ext_vector_type(4)));
typedef _Float16 half8 __attribute__((ext_vector_type(8)));
typedef __fp16 fp16x2 __attribute__((ext_vector_type(2)));   // cvt_pkrtz return type

__device__ inline unsigned short f2bf(float f) {
  union { float f; unsigned u; } c; c.f = f;
  unsigned u = c.u + 0x7FFF + ((c.u >> 16) & 1);
  return (unsigned short)(u >> 16);
}
__device__ inline float bf2f(unsigned short h) {
  union { unsigned u; float f; } c; c.u = ((unsigned)h) << 16;
  return c.f;
}
__device__ inline unsigned short f2h(float f) {
  union { _Float16 h; unsigned short u; } c; c.h = (_Float16)f; return c.u;
}
__device__ inline float h2f(unsigned short u) {
  union { unsigned short u; _Float16 h; } c; c.u = u; return (float)c.h;
}

// ---------------- workspace ----------------
constexpr size_t F_C0S = 0;
constexpr size_t F_C0Z = F_C0S + NROW;
constexpr size_t F_END = F_C0Z + NROW;
constexpr size_t U_CH  = 0;
constexpr size_t U_CL  = U_CH + (size_t)NROW * 64;
constexpr size_t U_BF  = U_CL + (size_t)NROW * 64;
constexpr size_t U_VF  = U_BF + (size_t)2 * 131072;

// ================================================================ mega launch 1
// blocks [0,64):   Bf basis-fragment table (fp16, single plane)
// blocks [64,576): kv V-fragment build (fp16; NEW s-order matching k4's
//                  in-register E-pack: k-slot (qd,j) <-> s = ksp*32 +
//                  (j>=4)*16 + qd*4 + (j&3))
// blocks [576,1088): fused DFT+coef (DFT in bf16-split, coefs emitted fp16 hi/lo)
__launch_bounds__(256)
__global__ void mega1(const float* __restrict__ q, const float* __restrict__ kin,
                      const float* __restrict__ values,
                      unsigned short* __restrict__ Bf, unsigned short* __restrict__ Vf,
                      unsigned short* __restrict__ Ch, unsigned short* __restrict__ Cl,
                      float* __restrict__ c0s) {
  __shared__ char smem[16896];
  int tid = threadIdx.x;
  int blk = blockIdx.x;
  if (blk < 64) {
    int gid = blk * 256 + tid;
    int lt = gid >> 7, rem = gid & 127, ks = rem >> 6, lane = rem & 63;
    int qd = lane >> 4, n = lane & 15;
    int t = lt * 16 + n;
    size_t base = ((size_t)((lt * 2 + ks) * 64 + lane)) * 8;
    for (int j = 0; j < 8; ++j) {
      int kr = ks * 32 + qd * 8 + j;
      int freq = (kr < 32) ? (kr + 1) : (kr - 31);
      int ph = (freq * t) & (CL - 1);
      float ang = (float)ph * (TWO_PI / (float)CL);
      float val = (kr < 32) ? cosf(ang) : sinf(ang);
      Bf[base + j] = f2h(val);
    }
    return;
  }
  if (blk < 576) {
    // V tile [64 s][64 d] -> B-operand frags (fp16): frag = dt*2+ksp;
    // elem[lane*8+j] = V[s = ksp*32 + (j>=4)*16 + qd*4 + (j&3)][d = dt*16 + n]
    float* Vt = (float*)smem;                    // [64][65]
    int idx = blk - 64;
    int bh = idx >> 5, st = idx & 31;
    int b = bh >> 3, h = bh & 7;
    {
      int sl = tid >> 2, dq = (tid & 3) * 16;
      const float4* src = (const float4*)(values + ((size_t)(b * 2048 + st * 64 + sl)) * 512 + h * 64 + dq);
#pragma unroll
      for (int m = 0; m < 4; ++m) {
        float4 t4 = src[m];
        int base = sl * 65 + dq + m * 4;
        Vt[base] = t4.x; Vt[base + 1] = t4.y; Vt[base + 2] = t4.z; Vt[base + 3] = t4.w;
      }
    }
    __syncthreads();
#pragma unroll
    for (int iter = 0; iter < 2; ++iter) {
      int it = iter * 256 + tid;
      int lane = it & 63, ksp = (it >> 6) & 1, dt = it >> 7;
      int qd = lane >> 4, n = lane & 15;
      int d = dt * 16 + n;
      short8 hi;
#pragma unroll
      for (int j = 0; j < 8; ++j)
        hi[j] = (short)f2h(Vt[(ksp * 32 + (j >> 2) * 16 + qd * 4 + (j & 3)) * 65 + d]);
      size_t off = (((size_t)(bh * 32 + st)) * 8 + dt * 2 + ksp) * 512 + lane * 8;
      *(short8*)(Vf + off) = hi;
    }
    return;
  }
  // ---- fused DFT + coef. Block = 8 s x 8 h of one b (64 rows).
  unsigned short* Tws = (unsigned short*)smem;   // 4 planes x 2048 (bf16 split)
  float* tab = (float*)(smem + 16384);           // 64 x {cos, sin}
  if (tid < 64) {
    float ang = (float)tid * (TWO_PI / 64.0f);
    float s1, c1;
    sincosf(ang, &s1, &c1);
    tab[tid * 2] = c1; tab[tid * 2 + 1] = s1;
  }
  __syncthreads();
  {
    int g0 = tid * 8;
    int lane_g = (g0 >> 3) & 63, ksp_g = (g0 >> 9) & 1, ct_g = g0 >> 10;
    int f = ct_g * 16 + (lane_g & 15);
    int cb = ksp_g * 32 + ((lane_g >> 4) & 3) * 8;
#pragma unroll
    for (int j = 0; j < 8; ++j) {
      int kk = (f * (cb + j)) & 63;
      float re = tab[kk * 2], im = -tab[kk * 2 + 1];
      unsigned short rh = f2bf(re), ih = f2bf(im);
      Tws[g0 + j] = rh;        Tws[2048 + g0 + j] = f2bf(re - bf2f(rh));
      Tws[4096 + g0 + j] = ih; Tws[6144 + g0 + j] = f2bf(im - bf2f(ih));
    }
  }
  __syncthreads();
  int w = tid >> 6, lane = tid & 63, qd = lane >> 4, n = lane & 15;
  int blk1 = blk - 576;
  int b = blk1 >> 8, s0 = (blk1 & 255) * 8;
  int sA = s0 + w * 2 + (n >> 3), hA = n & 7;
  const float* qp = q + ((size_t)(b * 2048 + sA)) * 512 + hA * 64 + qd * 8;
  const float* kp = kin + ((size_t)(b * 2048 + sA)) * 512 + hA * 64 + qd * 8;
  float qv[16], kv[16];
#pragma unroll
  for (int ksp = 0; ksp < 2; ++ksp) {
    float4 a0 = *(const float4*)(qp + ksp * 32);
    float4 a1 = *(const float4*)(qp + ksp * 32 + 4);
    float4 b0 = *(const float4*)(kp + ksp * 32);
    float4 b1 = *(const float4*)(kp + ksp * 32 + 4);
    qv[ksp*8+0]=a0.x; qv[ksp*8+1]=a0.y; qv[ksp*8+2]=a0.z; qv[ksp*8+3]=a0.w;
    qv[ksp*8+4]=a1.x; qv[ksp*8+5]=a1.y; qv[ksp*8+6]=a1.z; qv[ksp*8+7]=a1.w;
    kv[ksp*8+0]=b0.x; kv[ksp*8+1]=b0.y; kv[ksp*8+2]=b0.z; kv[ksp*8+3]=b0.w;
    kv[ksp*8+4]=b1.x; kv[ksp*8+5]=b1.y; kv[ksp*8+6]=b1.z; kv[ksp*8+7]=b1.w;
  }
  float aq = 0.0f, ak = 0.0f;
#pragma unroll
  for (int i = 0; i < 16; ++i) {
    float sg = (i & 1) ? -1.0f : 1.0f;
    aq += sg * qv[i]; ak += sg * kv[i];
  }
  aq += __shfl_xor(aq, 16); aq += __shfl_xor(aq, 32);
  ak += __shfl_xor(ak, 16); ak += __shfl_xor(ak, 32);
  short8 Aqh[2], Aql[2], Akh[2], Akl[2];
#pragma unroll
  for (int ksp = 0; ksp < 2; ++ksp) {
#pragma unroll
    for (int j = 0; j < 8; ++j) {
      unsigned short hq = f2bf(qv[ksp*8+j]);
      Aqh[ksp][j] = (short)hq; Aql[ksp][j] = (short)f2bf(qv[ksp*8+j] - bf2f(hq));
      unsigned short hk = f2bf(kv[ksp*8+j]);
      Akh[ksp][j] = (short)hk; Akl[ksp][j] = (short)f2bf(kv[ksp*8+j] - bf2f(hk));
    }
  }
  float lmr[4] = {0,0,0,0};
  float c0v[4] = {0,0,0,0};
  int hC = (qd * 4) & 7;
  int sC = s0 + w * 2 + (qd >> 1);
#pragma unroll
  for (int ct = 0; ct < 2; ++ct) {
    short8 Brh[2], Brl[2], Bih[2], Bil[2];
#pragma unroll
    for (int ksp = 0; ksp < 2; ++ksp) {
      size_t off = (size_t)ct * 1024 + ksp * 512 + lane * 8;
      Brh[ksp] = *(const short8*)(Tws + off);
      Brl[ksp] = *(const short8*)(Tws + 2048 + off);
      Bih[ksp] = *(const short8*)(Tws + 4096 + off);
      Bil[ksp] = *(const short8*)(Tws + 6144 + off);
    }
    floatx4 qre = {0,0,0,0}, qim = {0,0,0,0}, kre = {0,0,0,0}, kim = {0,0,0,0};
#pragma unroll
    for (int ksp = 0; ksp < 2; ++ksp) {
      qre = __builtin_amdgcn_mfma_f32_16x16x32_bf16(Aqh[ksp], Brh[ksp], qre, 0,0,0);
      qre = __builtin_amdgcn_mfma_f32_16x16x32_bf16(Aqh[ksp], Brl[ksp], qre, 0,0,0);
      qre = __builtin_amdgcn_mfma_f32_16x16x32_bf16(Aql[ksp], Brh[ksp], qre, 0,0,0);
      qim = __builtin_amdgcn_mfma_f32_16x16x32_bf16(Aqh[ksp], Bih[ksp], qim, 0,0,0);
      qim = __builtin_amdgcn_mfma_f32_16x16x32_bf16(Aqh[ksp], Bil[ksp], qim, 0,0,0);
      qim = __builtin_amdgcn_mfma_f32_16x16x32_bf16(Aql[ksp], Bih[ksp], qim, 0,0,0);
      kre = __builtin_amdgcn_mfma_f32_16x16x32_bf16(Akh[ksp], Brh[ksp], kre, 0,0,0);
      kre = __builtin_amdgcn_mfma_f32_16x16x32_bf16(Akh[ksp], Brl[ksp], kre, 0,0,0);
      kre = __builtin_amdgcn_mfma_f32_16x16x32_bf16(Akl[ksp], Brh[ksp], kre, 0,0,0);
      kim = __builtin_amdgcn_mfma_f32_16x16x32_bf16(Akh[ksp], Bih[ksp], kim, 0,0,0);
      kim = __builtin_amdgcn_mfma_f32_16x16x32_bf16(Akh[ksp], Bil[ksp], kim, 0,0,0);
      kim = __builtin_amdgcn_mfma_f32_16x16x32_bf16(Akl[ksp], Bih[ksp], kim, 0,0,0);
    }
    float xre[4], xim[4], tre = 0, tim = 0;
#pragma unroll
    for (int r = 0; r < 4; ++r) {
      xre[r] = qre[r] * kre[r] + qim[r] * kim[r];
      xim[r] = qim[r] * kre[r] - qre[r] * kim[r];
      tre += xre[r]; tim += xim[r];
    }
    tre += __shfl_xor(tre, 16);
    tim += __shfl_xor(tim, 16);
    float mre = tre * 0.125f, mim = tim * 0.125f;
#pragma unroll
    for (int r = 0; r < 4; ++r) {
      float yre = xre[r] - mre, yim = xim[r] - mim;
      if (ct == 0 && n == 0) {
        c0v[r] = yre * SCALE;
      } else {
        int f = ct * 16 + n;
        float a = 2.0f * yre * SCALE, bb = -2.0f * yim * SCALE;
        size_t rowid = (size_t)((b * 8 + hC + r) * 2048 + sC);
        unsigned short ah = f2h(a);
        Ch[rowid * 64 + f - 1] = ah;
        Cl[rowid * 64 + f - 1] = f2h(a - h2f(ah));
        unsigned short bh2 = f2h(bb);
        Ch[rowid * 64 + 32 + f - 1] = bh2;
        Cl[rowid * 64 + 32 + f - 1] = f2h(bb - h2f(bh2));
        lmr[r] += fabsf(a) + fabsf(bb);
      }
    }
  }
  float X32 = aq * ak;
  float m32 = X32;
  m32 += __shfl_xor(m32, 1); m32 += __shfl_xor(m32, 2); m32 += __shfl_xor(m32, 4);
  float A32 = 2.0f * (X32 - m32 * 0.125f) * SCALE;
  if (qd == 0) {
    size_t rowid = (size_t)((b * 8 + (n & 7)) * 2048 + s0 + w * 2 + (n >> 3));
    unsigned short ah = f2h(A32);
    Ch[rowid * 64 + 31] = ah;
    Cl[rowid * 64 + 31] = f2h(A32 - h2f(ah));
    Ch[rowid * 64 + 63] = 0;
    Cl[rowid * 64 + 63] = 0;
  }
  float absA32 = fabsf(A32);
#pragma unroll
  for (int r = 0; r < 4; ++r) {
    lmr[r] += __shfl_xor(lmr[r], 1);
    lmr[r] += __shfl_xor(lmr[r], 2);
    lmr[r] += __shfl_xor(lmr[r], 4);
    lmr[r] += __shfl_xor(lmr[r], 8);
  }
  int qb = lane & 48;
#pragma unroll
  for (int r = 0; r < 4; ++r) {
    float a32r = __shfl(absA32, qb + (qb >> 2) + r);
    if (n == 0) {
      float M = fabsf(c0v[r]) + lmr[r] + a32r;
      size_t rowid = (size_t)((b * 8 + hC + r) * 2048 + sC);
      c0s[rowid] = c0v[r] - M;
    }
  }
}

// ---------------------------------------------------------------- k3: c0z = c0 - log(Z)
// fp16 logit GEMM: 4 MFMA per (c, lt). 512 threads / 8 waves per block.
__launch_bounds__(512)
__global__ void k3_z(const unsigned short* __restrict__ Ch, const unsigned short* __restrict__ Cl,
                     const float* __restrict__ c0s, const unsigned short* __restrict__ Bf,
                     float* __restrict__ c0z) {
  __shared__ float Zl[64];
  int tid = threadIdx.x;
  int w = tid >> 6, lane = tid & 63, q = lane >> 4, n = lane & 15;
  int rowbase = blockIdx.x * 64;
  half8 Ah[4][2], Al[4][2];
#pragma unroll
  for (int c = 0; c < 4; ++c)
#pragma unroll
    for (int ksp = 0; ksp < 2; ++ksp) {
      size_t srow = (size_t)(rowbase + c * 16 + n);
      Ah[c][ksp] = *(const half8*)(Ch + srow * 64 + ksp * 32 + q * 8);
      Al[c][ksp] = *(const half8*)(Cl + srow * 64 + ksp * 32 + q * 8);
    }
  float c0r[4][4], zacc[4][4];
#pragma unroll
  for (int c = 0; c < 4; ++c)
#pragma unroll
    for (int r = 0; r < 4; ++r) {
      c0r[c][r] = c0s[rowbase + c * 16 + q * 4 + r];
      zacc[c][r] = 0.0f;
    }
  if (tid < 64) Zl[tid] = 0.0f;
  for (int lt = w; lt < 128; lt += 8) {
    size_t b0 = ((size_t)(lt * 2 + 0) * 64 + lane) * 8;
    size_t b1 = ((size_t)(lt * 2 + 1) * 64 + lane) * 8;
    half8 Bh0 = *(const half8*)(Bf + b0);
    half8 Bh1 = *(const half8*)(Bf + b1);
#pragma unroll
    for (int c = 0; c < 4; ++c) {
      floatx4 y = {0.f, 0.f, 0.f, 0.f};
      y = __builtin_amdgcn_mfma_f32_16x16x32_f16(Ah[c][0], Bh0, y, 0, 0, 0);
      y = __builtin_amdgcn_mfma_f32_16x16x32_f16(Ah[c][1], Bh1, y, 0, 0, 0);
      y = __builtin_amdgcn_mfma_f32_16x16x32_f16(Al[c][0], Bh0, y, 0, 0, 0);
      y = __builtin_amdgcn_mfma_f32_16x16x32_f16(Al[c][1], Bh1, y, 0, 0, 0);
#pragma unroll
      for (int r = 0; r < 4; ++r) zacc[c][r] += __expf(y[r] + c0r[c][r]);
    }
  }
  __syncthreads();
#pragma unroll
  for (int c = 0; c < 4; ++c)
#pragma unroll
    for (int r = 0; r < 4; ++r) {
#pragma unroll
      for (int m = 1; m < 16; m <<= 1) zacc[c][r] += __shfl_xor(zacc[c][r], m, 16);
      if (n == 0) atomicAdd(&Zl[c * 16 + q * 4 + r], zacc[c][r]);
    }
  __syncthreads();
  if (tid < 64) c0z[rowbase + tid] = c0s[rowbase + tid] - __logf(Zl[tid]);
}

// ---------------------------------------------------------------- k4: output
// R4 REWRITE: barrier-free. Waves own s-slices (not d-slices); the E-GEMM
// 16x16 output packs (cvt_pkrtz) DIRECTLY into the PV k=32 A-fragment in the
// SAME lanes (A row = lane&15 = t = E-out col; A k-slot (g,j) <-> s =
// (j>=4)*16 + 4g + (j&3), an ordering the Vf build matches). No Es LDS, no
// per-tile barrier, no lockstep: per-wave partial accv, one 2-barrier LDS
// reduce at the end. (R0-R3 evidence: time invariant to occupancy & barrier
// flavor => the 2-phase lockstep structure itself was the ceiling.)
#define NLOADA(it_, B_)                                                              \
  do {                                                                               \
    int sb_ = (it_) * 128 + w * 32;                                                  \
    size_t r0_ = (size_t)(bh * 2048 + sb_ + n);                                      \
    size_t r1_ = r0_ + 16;                                                           \
    Ah[B_][0][0] = *(const half8*)(Ch + r0_ * 64 + qd * 8);                          \
    Ah[B_][0][1] = *(const half8*)(Ch + r0_ * 64 + 32 + qd * 8);                     \
    Ah[B_][1][0] = *(const half8*)(Ch + r1_ * 64 + qd * 8);                          \
    Ah[B_][1][1] = *(const half8*)(Ch + r1_ * 64 + 32 + qd * 8);                     \
    Al[B_][0][0] = *(const half8*)(Cl + r0_ * 64 + qd * 8);                          \
    Al[B_][0][1] = *(const half8*)(Cl + r0_ * 64 + 32 + qd * 8);                     \
    Al[B_][1][0] = *(const half8*)(Cl + r1_ * 64 + qd * 8);                          \
    Al[B_][1][1] = *(const half8*)(Cl + r1_ * 64 + 32 + qd * 8);                     \
    cc[B_][0] = *(const float4*)(c0z + bh * 2048 + sb_ + qd * 4);                    \
    cc[B_][1] = *(const float4*)(c0z + bh * 2048 + sb_ + 16 + qd * 4);               \
  } while (0)

#define NLOADV(it_)                                                                  \
  do {                                                                               \
    int st32_ = (it_) * 4 + w;                                                       \
    size_t vb_ = (((size_t)(bh * 32 + (st32_ >> 1))) * 8 + (st32_ & 1)) * 512 + lane * 8; \
    Vh[0] = *(const half8*)(Vf + vb_);                                               \
    Vh[1] = *(const half8*)(Vf + vb_ + 1024);                                        \
    Vh[2] = *(const half8*)(Vf + vb_ + 2048);                                        \
    Vh[3] = *(const half8*)(Vf + vb_ + 3072);                                        \
  } while (0)

#define NCOMP(B_)                                                                    \
  do {                                                                               \
    _Pragma("unroll")                                                                \
    for (int lt_ = 0; lt_ < 4; ++lt_) {                                              \
      floatx4 y0 = {0, 0, 0, 0}, y1 = {0, 0, 0, 0};                                  \
      y0 = __builtin_amdgcn_mfma_f32_16x16x32_f16(Ah[B_][0][0], Bb[lt_][0], y0, 0, 0, 0); \
      y0 = __builtin_amdgcn_mfma_f32_16x16x32_f16(Ah[B_][0][1], Bb[lt_][1], y0, 0, 0, 0); \
      y0 = __builtin_amdgcn_mfma_f32_16x16x32_f16(Al[B_][0][0], Bb[lt_][0], y0, 0, 0, 0); \
      y0 = __builtin_amdgcn_mfma_f32_16x16x32_f16(Al[B_][0][1], Bb[lt_][1], y0, 0, 0, 0); \
      y1 = __builtin_amdgcn_mfma_f32_16x16x32_f16(Ah[B_][1][0], Bb[lt_][0], y1, 0, 0, 0); \
      y1 = __builtin_amdgcn_mfma_f32_16x16x32_f16(Ah[B_][1][1], Bb[lt_][1], y1, 0, 0, 0); \
      y1 = __builtin_amdgcn_mfma_f32_16x16x32_f16(Al[B_][1][0], Bb[lt_][0], y1, 0, 0, 0); \
      y1 = __builtin_amdgcn_mfma_f32_16x16x32_f16(Al[B_][1][1], Bb[lt_][1], y1, 0, 0, 0); \
      union { fp16x2 h; unsigned u; } p0_, p1_, p2_, p3_;                            \
      p0_.h = __builtin_amdgcn_cvt_pkrtz(__expf(y0[0] + cc[B_][0].x), __expf(y0[1] + cc[B_][0].y)); \
      p1_.h = __builtin_amdgcn_cvt_pkrtz(__expf(y0[2] + cc[B_][0].z), __expf(y0[3] + cc[B_][0].w)); \
      p2_.h = __builtin_amdgcn_cvt_pkrtz(__expf(y1[0] + cc[B_][1].x), __expf(y1[1] + cc[B_][1].y)); \
      p3_.h = __builtin_amdgcn_cvt_pkrtz(__expf(y1[2] + cc[B_][1].z), __expf(y1[3] + cc[B_][1].w)); \
      union { unsigned u4[4]; half8 h8; } pa_;                                       \
      pa_.u4[0] = p0_.u; pa_.u4[1] = p1_.u; pa_.u4[2] = p2_.u; pa_.u4[3] = p3_.u;    \
      _Pragma("unroll")                                                              \
      for (int dt_ = 0; dt_ < 4; ++dt_)                                              \
        accv[lt_][dt_] = __builtin_amdgcn_mfma_f32_16x16x32_f16(pa_.h8, Vh[dt_], accv[lt_][dt_], 0, 0, 0); \
    }                                                                                \
  } while (0)

#define NSTEP(it_, CUR_, NXT_, last_)                                                \
  do {                                                                               \
    NLOADV(it_);                                                                     \
    if (!(last_)) { NLOADA((it_) + 1, NXT_); }                                       \
    NCOMP(CUR_);                                                                     \
  } while (0)

__launch_bounds__(256, 2)
__global__ void k4_out(const unsigned short* __restrict__ Ch, const unsigned short* __restrict__ Cl,
                       const float* __restrict__ c0z, const unsigned short* __restrict__ Bf,
                       const unsigned short* __restrict__ Vf, float* __restrict__ out) {
  __shared__ float Ld[2][64 * 65];
  int tid = threadIdx.x;
  int w = tid >> 6, lane = tid & 63, qd = lane >> 4, n = lane & 15;
  int bid = blockIdx.x;
  // XCD colocation: 2 bh per XCD -> Ch/Cl/Vf working set ~2.6 MB fits 4 MB L2.
  int xcd = bid & 7, idx = bid >> 3;
  int bh = (xcd << 1) | (idx >> 5), lb = idx & 31;
  int b = bh >> 3, h = bh & 7;
  int l0 = lb * 64;
  half8 Bb[4][2];
#pragma unroll
  for (int lt = 0; lt < 4; ++lt)
#pragma unroll
    for (int ksp = 0; ksp < 2; ++ksp) {
      size_t bo = ((size_t)((lb * 4 + lt) * 2 + ksp) * 64 + lane) * 8;
      Bb[lt][ksp] = *(const half8*)(Bf + bo);
    }
  floatx4 accv[4][4];
#pragma unroll
  for (int lt = 0; lt < 4; ++lt)
#pragma unroll
    for (int dt = 0; dt < 4; ++dt) accv[lt][dt] = (floatx4){0.f, 0.f, 0.f, 0.f};
  half8 Ah[2][2][2], Al[2][2][2], Vh[4];
  float4 cc[2][2];
  NLOADA(0, 0);
  NSTEP(0, 0, 1, false);   NSTEP(1, 1, 0, false);
  NSTEP(2, 0, 1, false);   NSTEP(3, 1, 0, false);
  NSTEP(4, 0, 1, false);   NSTEP(5, 1, 0, false);
  NSTEP(6, 0, 1, false);   NSTEP(7, 1, 0, false);
  NSTEP(8, 0, 1, false);   NSTEP(9, 1, 0, false);
  NSTEP(10, 0, 1, false);  NSTEP(11, 1, 0, false);
  NSTEP(12, 0, 1, false);  NSTEP(13, 1, 0, false);
  NSTEP(14, 0, 1, false);  NSTEP(15, 1, 0, true);
  // ---- cross-wave s-reduction (2 barriers total) ----
  if (w & 1) {   // waves 1,3 -> planes 0,1
    int p = w >> 1;
#pragma unroll
    for (int lt = 0; lt < 4; ++lt)
#pragma unroll
      for (int dt = 0; dt < 4; ++dt)
#pragma unroll
        for (int r = 0; r < 4; ++r)
          Ld[p][(lt * 16 + qd * 4 + r) * 65 + dt * 16 + n] = accv[lt][dt][r];
  }
  __syncthreads();
  if (!(w & 1)) {  // waves 0,2: add partner plane, write summed half
    int p = w >> 1;
#pragma unroll
    for (int lt = 0; lt < 4; ++lt)
#pragma unroll
      for (int dt = 0; dt < 4; ++dt)
#pragma unroll
        for (int r = 0; r < 4; ++r) {
          int off = (lt * 16 + qd * 4 + r) * 65 + dt * 16 + n;
          Ld[p][off] += accv[lt][dt][r];
        }
  }
  __syncthreads();
  // cooperative coalesced store: thread (dd, to) -> row d=dd, l-range to*16..+15
  int to = tid & 3, dd = tid >> 2;
  size_t ob = ((size_t)((b * 64 + dd) * 8 + h)) * 2048 + l0 + to * 16;
#pragma unroll
  for (int jq = 0; jq < 4; ++jq) {
    int t0 = to * 16 + jq * 4;
    float4 o4;
    o4.x = Ld[0][(t0 + 0) * 65 + dd] + Ld[1][(t0 + 0) * 65 + dd];
    o4.y = Ld[0][(t0 + 1) * 65 + dd] + Ld[1][(t0 + 1) * 65 + dd];
    o4.z = Ld[0][(t0 + 2) * 65 + dd] + Ld[1][(t0 + 2) * 65 + dd];
    o4.w = Ld[0][(t0 + 3) * 65 + dd] + Ld[1][(t0 + 3) * 65 + dd];
    *(float4*)(out + ob + jq * 4) = o4;
  }
}

extern "C" void kernel_launch(void* const* d_in, const int* in_sizes, int n_in,
                              void* d_out, int out_size, void* d_ws, size_t ws_size,
                              hipStream_t stream) {
  const float* q = (const float*)d_in[0];
  const float* k = (const float*)d_in[1];
  const float* v = (const float*)d_in[2];
  float* out = (float*)d_out;
  float* ws = (float*)d_ws;
  float* c0s = ws + F_C0S;
  float* c0z = ws + F_C0Z;
  unsigned short* ubase = (unsigned short*)(ws + F_END);
  unsigned short* Ch = ubase + U_CH;
  unsigned short* Cl = ubase + U_CL;
  unsigned short* Bf = ubase + U_BF;
  unsigned short* Vf = ubase + U_VF;

  mega1<<<dim3(1088), dim3(256), 0, stream>>>(q, k, v, Bf, Vf, Ch, Cl, c0s);
  k3_z<<<dim3(512), dim3(512), 0, stream>>>(Ch, Cl, c0s, Bf, c0z);
  k4_out<<<dim3(512), dim3(256), 0, stream>>>(Ch, Cl, c0z, Bf, Vf, out);
}

// Round 6
// 145.590 us; speedup vs baseline: 1.0225x; 1.0127x over previous
//
#include <hip/hip_runtime.h>
#include <math.h>

// B=2, H=8, L=2048, E=512, d=64
constexpr int CL = 2048;
constexpr int NROW = 32768;
constexpr float SCALE = 1.0f / 2048.0f;
constexpr float TWO_PI = 6.283185307179586f;

typedef short short8 __attribute__((ext_vector_type(8)));
typedef float floatx4 __attribute__((ext_vector_type(4)));
typedef _Float16 half8 __attribute__((ext_vector_type(8)));
typedef __fp16 fp16x2 __attribute__((ext_vector_type(2)));   // cvt_pkrtz return type

__device__ inline unsigned short f2bf(float f) {
  union { float f; unsigned u; } c; c.f = f;
  unsigned u = c.u + 0x7FFF + ((c.u >> 16) & 1);
  return (unsigned short)(u >> 16);
}
__device__ inline float bf2f(unsigned short h) {
  union { unsigned u; float f; } c; c.u = ((unsigned)h) << 16;
  return c.f;
}
__device__ inline unsigned short f2h(float f) {
  union { _Float16 h; unsigned short u; } c; c.h = (_Float16)f; return c.u;
}
__device__ inline float h2f(unsigned short u) {
  union { unsigned short u; _Float16 h; } c; c.u = u; return (float)c.h;
}

// ---------------- workspace ----------------
constexpr size_t F_C0S = 0;
constexpr size_t F_C0Z = F_C0S + NROW;
constexpr size_t F_END = F_C0Z + NROW;
constexpr size_t U_CH  = 0;
constexpr size_t U_CL  = U_CH + (size_t)NROW * 64;
constexpr size_t U_BF  = U_CL + (size_t)NROW * 64;
constexpr size_t U_VF  = U_BF + (size_t)2 * 131072;

// ================================================================ mega launch 1
// blocks [0,64):   Bf basis-fragment table (fp16, single plane)
// blocks [64,576): kv V-fragment build (fp16; s-order matching k4's
//                  in-register E-pack: k-slot (qd,j) <-> s = ksp*32 +
//                  (j>=4)*16 + qd*4 + (j&3))
// blocks [576,1088): fused DFT+coef (DFT in bf16-split, coefs emitted fp16 hi/lo)
__launch_bounds__(256)
__global__ void mega1(const float* __restrict__ q, const float* __restrict__ kin,
                      const float* __restrict__ values,
                      unsigned short* __restrict__ Bf, unsigned short* __restrict__ Vf,
                      unsigned short* __restrict__ Ch, unsigned short* __restrict__ Cl,
                      float* __restrict__ c0s) {
  __shared__ char smem[16896];
  int tid = threadIdx.x;
  int blk = blockIdx.x;
  if (blk < 64) {
    int gid = blk * 256 + tid;
    int lt = gid >> 7, rem = gid & 127, ks = rem >> 6, lane = rem & 63;
    int qd = lane >> 4, n = lane & 15;
    int t = lt * 16 + n;
    size_t base = ((size_t)((lt * 2 + ks) * 64 + lane)) * 8;
    for (int j = 0; j < 8; ++j) {
      int kr = ks * 32 + qd * 8 + j;
      int freq = (kr < 32) ? (kr + 1) : (kr - 31);
      int ph = (freq * t) & (CL - 1);
      float ang = (float)ph * (TWO_PI / (float)CL);
      float val = (kr < 32) ? cosf(ang) : sinf(ang);
      Bf[base + j] = f2h(val);
    }
    return;
  }
  if (blk < 576) {
    // V tile [64 s][64 d] -> B-operand frags (fp16): frag = dt*2+ksp;
    // elem[lane*8+j] = V[s = ksp*32 + (j>=4)*16 + qd*4 + (j&3)][d = dt*16 + n]
    float* Vt = (float*)smem;                    // [64][65]
    int idx = blk - 64;
    int bh = idx >> 5, st = idx & 31;
    int b = bh >> 3, h = bh & 7;
    {
      int sl = tid >> 2, dq = (tid & 3) * 16;
      const float4* src = (const float4*)(values + ((size_t)(b * 2048 + st * 64 + sl)) * 512 + h * 64 + dq);
#pragma unroll
      for (int m = 0; m < 4; ++m) {
        float4 t4 = src[m];
        int base = sl * 65 + dq + m * 4;
        Vt[base] = t4.x; Vt[base + 1] = t4.y; Vt[base + 2] = t4.z; Vt[base + 3] = t4.w;
      }
    }
    __syncthreads();
#pragma unroll
    for (int iter = 0; iter < 2; ++iter) {
      int it = iter * 256 + tid;
      int lane = it & 63, ksp = (it >> 6) & 1, dt = it >> 7;
      int qd = lane >> 4, n = lane & 15;
      int d = dt * 16 + n;
      short8 hi;
#pragma unroll
      for (int j = 0; j < 8; ++j)
        hi[j] = (short)f2h(Vt[(ksp * 32 + (j >> 2) * 16 + qd * 4 + (j & 3)) * 65 + d]);
      size_t off = (((size_t)(bh * 32 + st)) * 8 + dt * 2 + ksp) * 512 + lane * 8;
      *(short8*)(Vf + off) = hi;
    }
    return;
  }
  // ---- fused DFT + coef. Block = 8 s x 8 h of one b (64 rows).
  unsigned short* Tws = (unsigned short*)smem;   // 4 planes x 2048 (bf16 split)
  float* tab = (float*)(smem + 16384);           // 64 x {cos, sin}
  if (tid < 64) {
    float ang = (float)tid * (TWO_PI / 64.0f);
    float s1, c1;
    sincosf(ang, &s1, &c1);
    tab[tid * 2] = c1; tab[tid * 2 + 1] = s1;
  }
  __syncthreads();
  {
    int g0 = tid * 8;
    int lane_g = (g0 >> 3) & 63, ksp_g = (g0 >> 9) & 1, ct_g = g0 >> 10;
    int f = ct_g * 16 + (lane_g & 15);
    int cb = ksp_g * 32 + ((lane_g >> 4) & 3) * 8;
#pragma unroll
    for (int j = 0; j < 8; ++j) {
      int kk = (f * (cb + j)) & 63;
      float re = tab[kk * 2], im = -tab[kk * 2 + 1];
      unsigned short rh = f2bf(re), ih = f2bf(im);
      Tws[g0 + j] = rh;        Tws[2048 + g0 + j] = f2bf(re - bf2f(rh));
      Tws[4096 + g0 + j] = ih; Tws[6144 + g0 + j] = f2bf(im - bf2f(ih));
    }
  }
  __syncthreads();
  int w = tid >> 6, lane = tid & 63, qd = lane >> 4, n = lane & 15;
  int blk1 = blk - 576;
  int b = blk1 >> 8, s0 = (blk1 & 255) * 8;
  int sA = s0 + w * 2 + (n >> 3), hA = n & 7;
  const float* qp = q + ((size_t)(b * 2048 + sA)) * 512 + hA * 64 + qd * 8;
  const float* kp = kin + ((size_t)(b * 2048 + sA)) * 512 + hA * 64 + qd * 8;
  float qv[16], kv[16];
#pragma unroll
  for (int ksp = 0; ksp < 2; ++ksp) {
    float4 a0 = *(const float4*)(qp + ksp * 32);
    float4 a1 = *(const float4*)(qp + ksp * 32 + 4);
    float4 b0 = *(const float4*)(kp + ksp * 32);
    float4 b1 = *(const float4*)(kp + ksp * 32 + 4);
    qv[ksp*8+0]=a0.x; qv[ksp*8+1]=a0.y; qv[ksp*8+2]=a0.z; qv[ksp*8+3]=a0.w;
    qv[ksp*8+4]=a1.x; qv[ksp*8+5]=a1.y; qv[ksp*8+6]=a1.z; qv[ksp*8+7]=a1.w;
    kv[ksp*8+0]=b0.x; kv[ksp*8+1]=b0.y; kv[ksp*8+2]=b0.z; kv[ksp*8+3]=b0.w;
    kv[ksp*8+4]=b1.x; kv[ksp*8+5]=b1.y; kv[ksp*8+6]=b1.z; kv[ksp*8+7]=b1.w;
  }
  float aq = 0.0f, ak = 0.0f;
#pragma unroll
  for (int i = 0; i < 16; ++i) {
    float sg = (i & 1) ? -1.0f : 1.0f;
    aq += sg * qv[i]; ak += sg * kv[i];
  }
  aq += __shfl_xor(aq, 16); aq += __shfl_xor(aq, 32);
  ak += __shfl_xor(ak, 16); ak += __shfl_xor(ak, 32);
  short8 Aqh[2], Aql[2], Akh[2], Akl[2];
#pragma unroll
  for (int ksp = 0; ksp < 2; ++ksp) {
#pragma unroll
    for (int j = 0; j < 8; ++j) {
      unsigned short hq = f2bf(qv[ksp*8+j]);
      Aqh[ksp][j] = (short)hq; Aql[ksp][j] = (short)f2bf(qv[ksp*8+j] - bf2f(hq));
      unsigned short hk = f2bf(kv[ksp*8+j]);
      Akh[ksp][j] = (short)hk; Akl[ksp][j] = (short)f2bf(kv[ksp*8+j] - bf2f(hk));
    }
  }
  float lmr[4] = {0,0,0,0};
  float c0v[4] = {0,0,0,0};
  int hC = (qd * 4) & 7;
  int sC = s0 + w * 2 + (qd >> 1);
#pragma unroll
  for (int ct = 0; ct < 2; ++ct) {
    short8 Brh[2], Brl[2], Bih[2], Bil[2];
#pragma unroll
    for (int ksp = 0; ksp < 2; ++ksp) {
      size_t off = (size_t)ct * 1024 + ksp * 512 + lane * 8;
      Brh[ksp] = *(const short8*)(Tws + off);
      Brl[ksp] = *(const short8*)(Tws + 2048 + off);
      Bih[ksp] = *(const short8*)(Tws + 4096 + off);
      Bil[ksp] = *(const short8*)(Tws + 6144 + off);
    }
    floatx4 qre = {0,0,0,0}, qim = {0,0,0,0}, kre = {0,0,0,0}, kim = {0,0,0,0};
#pragma unroll
    for (int ksp = 0; ksp < 2; ++ksp) {
      qre = __builtin_amdgcn_mfma_f32_16x16x32_bf16(Aqh[ksp], Brh[ksp], qre, 0,0,0);
      qre = __builtin_amdgcn_mfma_f32_16x16x32_bf16(Aqh[ksp], Brl[ksp], qre, 0,0,0);
      qre = __builtin_amdgcn_mfma_f32_16x16x32_bf16(Aql[ksp], Brh[ksp], qre, 0,0,0);
      qim = __builtin_amdgcn_mfma_f32_16x16x32_bf16(Aqh[ksp], Bih[ksp], qim, 0,0,0);
      qim = __builtin_amdgcn_mfma_f32_16x16x32_bf16(Aqh[ksp], Bil[ksp], qim, 0,0,0);
      qim = __builtin_amdgcn_mfma_f32_16x16x32_bf16(Aql[ksp], Bih[ksp], qim, 0,0,0);
      kre = __builtin_amdgcn_mfma_f32_16x16x32_bf16(Akh[ksp], Brh[ksp], kre, 0,0,0);
      kre = __builtin_amdgcn_mfma_f32_16x16x32_bf16(Akh[ksp], Brl[ksp], kre, 0,0,0);
      kre = __builtin_amdgcn_mfma_f32_16x16x32_bf16(Akl[ksp], Brh[ksp], kre, 0,0,0);
      kim = __builtin_amdgcn_mfma_f32_16x16x32_bf16(Akh[ksp], Bih[ksp], kim, 0,0,0);
      kim = __builtin_amdgcn_mfma_f32_16x16x32_bf16(Akh[ksp], Bil[ksp], kim, 0,0,0);
      kim = __builtin_amdgcn_mfma_f32_16x16x32_bf16(Akl[ksp], Bih[ksp], kim, 0,0,0);
    }
    float xre[4], xim[4], tre = 0, tim = 0;
#pragma unroll
    for (int r = 0; r < 4; ++r) {
      xre[r] = qre[r] * kre[r] + qim[r] * kim[r];
      xim[r] = qim[r] * kre[r] - qre[r] * kim[r];
      tre += xre[r]; tim += xim[r];
    }
    tre += __shfl_xor(tre, 16);
    tim += __shfl_xor(tim, 16);
    float mre = tre * 0.125f, mim = tim * 0.125f;
#pragma unroll
    for (int r = 0; r < 4; ++r) {
      float yre = xre[r] - mre, yim = xim[r] - mim;
      if (ct == 0 && n == 0) {
        c0v[r] = yre * SCALE;
      } else {
        int f = ct * 16 + n;
        float a = 2.0f * yre * SCALE, bb = -2.0f * yim * SCALE;
        size_t rowid = (size_t)((b * 8 + hC + r) * 2048 + sC);
        unsigned short ah = f2h(a);
        Ch[rowid * 64 + f - 1] = ah;
        Cl[rowid * 64 + f - 1] = f2h(a - h2f(ah));
        unsigned short bh2 = f2h(bb);
        Ch[rowid * 64 + 32 + f - 1] = bh2;
        Cl[rowid * 64 + 32 + f - 1] = f2h(bb - h2f(bh2));
        lmr[r] += fabsf(a) + fabsf(bb);
      }
    }
  }
  float X32 = aq * ak;
  float m32 = X32;
  m32 += __shfl_xor(m32, 1); m32 += __shfl_xor(m32, 2); m32 += __shfl_xor(m32, 4);
  float A32 = 2.0f * (X32 - m32 * 0.125f) * SCALE;
  if (qd == 0) {
    size_t rowid = (size_t)((b * 8 + (n & 7)) * 2048 + s0 + w * 2 + (n >> 3));
    unsigned short ah = f2h(A32);
    Ch[rowid * 64 + 31] = ah;
    Cl[rowid * 64 + 31] = f2h(A32 - h2f(ah));
    Ch[rowid * 64 + 63] = 0;
    Cl[rowid * 64 + 63] = 0;
  }
  float absA32 = fabsf(A32);
#pragma unroll
  for (int r = 0; r < 4; ++r) {
    lmr[r] += __shfl_xor(lmr[r], 1);
    lmr[r] += __shfl_xor(lmr[r], 2);
    lmr[r] += __shfl_xor(lmr[r], 4);
    lmr[r] += __shfl_xor(lmr[r], 8);
  }
  int qb = lane & 48;
#pragma unroll
  for (int r = 0; r < 4; ++r) {
    float a32r = __shfl(absA32, qb + (qb >> 2) + r);
    if (n == 0) {
      float M = fabsf(c0v[r]) + lmr[r] + a32r;
      size_t rowid = (size_t)((b * 8 + hC + r) * 2048 + sC);
      c0s[rowid] = c0v[r] - M;
    }
  }
}

// ---------------------------------------------------------------- k3: c0z = c0 - log(Z)
// fp16 logit GEMM: 4 MFMA per (c, lt). 512 threads / 8 waves per block.
__launch_bounds__(512)
__global__ void k3_z(const unsigned short* __restrict__ Ch, const unsigned short* __restrict__ Cl,
                     const float* __restrict__ c0s, const unsigned short* __restrict__ Bf,
                     float* __restrict__ c0z) {
  __shared__ float Zl[64];
  int tid = threadIdx.x;
  int w = tid >> 6, lane = tid & 63, q = lane >> 4, n = lane & 15;
  int rowbase = blockIdx.x * 64;
  half8 Ah[4][2], Al[4][2];
#pragma unroll
  for (int c = 0; c < 4; ++c)
#pragma unroll
    for (int ksp = 0; ksp < 2; ++ksp) {
      size_t srow = (size_t)(rowbase + c * 16 + n);
      Ah[c][ksp] = *(const half8*)(Ch + srow * 64 + ksp * 32 + q * 8);
      Al[c][ksp] = *(const half8*)(Cl + srow * 64 + ksp * 32 + q * 8);
    }
  float c0r[4][4], zacc[4][4];
#pragma unroll
  for (int c = 0; c < 4; ++c)
#pragma unroll
    for (int r = 0; r < 4; ++r) {
      c0r[c][r] = c0s[rowbase + c * 16 + q * 4 + r];
      zacc[c][r] = 0.0f;
    }
  if (tid < 64) Zl[tid] = 0.0f;
  for (int lt = w; lt < 128; lt += 8) {
    size_t b0 = ((size_t)(lt * 2 + 0) * 64 + lane) * 8;
    size_t b1 = ((size_t)(lt * 2 + 1) * 64 + lane) * 8;
    half8 Bh0 = *(const half8*)(Bf + b0);
    half8 Bh1 = *(const half8*)(Bf + b1);
#pragma unroll
    for (int c = 0; c < 4; ++c) {
      floatx4 y = {0.f, 0.f, 0.f, 0.f};
      y = __builtin_amdgcn_mfma_f32_16x16x32_f16(Ah[c][0], Bh0, y, 0, 0, 0);
      y = __builtin_amdgcn_mfma_f32_16x16x32_f16(Ah[c][1], Bh1, y, 0, 0, 0);
      y = __builtin_amdgcn_mfma_f32_16x16x32_f16(Al[c][0], Bh0, y, 0, 0, 0);
      y = __builtin_amdgcn_mfma_f32_16x16x32_f16(Al[c][1], Bh1, y, 0, 0, 0);
#pragma unroll
      for (int r = 0; r < 4; ++r) zacc[c][r] += __expf(y[r] + c0r[c][r]);
    }
  }
  __syncthreads();
#pragma unroll
  for (int c = 0; c < 4; ++c)
#pragma unroll
    for (int r = 0; r < 4; ++r) {
#pragma unroll
      for (int m = 1; m < 16; m <<= 1) zacc[c][r] += __shfl_xor(zacc[c][r], m, 16);
      if (n == 0) atomicAdd(&Zl[c * 16 + q * 4 + r], zacc[c][r]);
    }
  __syncthreads();
  if (tid < 64) c0z[rowbase + tid] = c0s[rowbase + tid] - __logf(Zl[tid]);
}

// ---------------------------------------------------------------- k4: output
// Barrier-free s-slice structure (R4) with the main loop ROLLED (R5).
// R4 post-mortem: fully-unrolled 16 steps ~= 32+KB code > 32KB L1I; waves
// drift (no barriers) and thrash I-cache independently -> both pipes idle
// (MfmaUtil 13.7 / VALUBusy 15.6) and 68us. Rolled 2-step body ~4KB fits
// L1I; double-buffer slot indices stay compile-time (rule #20).
#define NLOADA(it_, B_)                                                              \
  do {                                                                               \
    int sb_ = (it_) * 128 + w * 32;                                                  \
    size_t r0_ = (size_t)(bh * 2048 + sb_ + n);                                      \
    size_t r1_ = r0_ + 16;                                                           \
    Ah[B_][0][0] = *(const half8*)(Ch + r0_ * 64 + qd * 8);                          \
    Ah[B_][0][1] = *(const half8*)(Ch + r0_ * 64 + 32 + qd * 8);                     \
    Ah[B_][1][0] = *(const half8*)(Ch + r1_ * 64 + qd * 8);                          \
    Ah[B_][1][1] = *(const half8*)(Ch + r1_ * 64 + 32 + qd * 8);                     \
    Al[B_][0][0] = *(const half8*)(Cl + r0_ * 64 + qd * 8);                          \
    Al[B_][0][1] = *(const half8*)(Cl + r0_ * 64 + 32 + qd * 8);                     \
    Al[B_][1][0] = *(const half8*)(Cl + r1_ * 64 + qd * 8);                          \
    Al[B_][1][1] = *(const half8*)(Cl + r1_ * 64 + 32 + qd * 8);                     \
    cc[B_][0] = *(const float4*)(c0z + bh * 2048 + sb_ + qd * 4);                    \
    cc[B_][1] = *(const float4*)(c0z + bh * 2048 + sb_ + 16 + qd * 4);               \
  } while (0)

#define NLOADV(it_)                                                                  \
  do {                                                                               \
    int st32_ = (it_) * 4 + w;                                                       \
    size_t vb_ = (((size_t)(bh * 32 + (st32_ >> 1))) * 8 + (st32_ & 1)) * 512 + lane * 8; \
    Vh[0] = *(const half8*)(Vf + vb_);                                               \
    Vh[1] = *(const half8*)(Vf + vb_ + 1024);                                        \
    Vh[2] = *(const half8*)(Vf + vb_ + 2048);                                        \
    Vh[3] = *(const half8*)(Vf + vb_ + 3072);                                        \
  } while (0)

#define NCOMP(B_)                                                                    \
  do {                                                                               \
    _Pragma("unroll")                                                                \
    for (int lt_ = 0; lt_ < 4; ++lt_) {                                              \
      floatx4 y0 = {0, 0, 0, 0}, y1 = {0, 0, 0, 0};                                  \
      y0 = __builtin_amdgcn_mfma_f32_16x16x32_f16(Ah[B_][0][0], Bb[lt_][0], y0, 0, 0, 0); \
      y0 = __builtin_amdgcn_mfma_f32_16x16x32_f16(Ah[B_][0][1], Bb[lt_][1], y0, 0, 0, 0); \
      y0 = __builtin_amdgcn_mfma_f32_16x16x32_f16(Al[B_][0][0], Bb[lt_][0], y0, 0, 0, 0); \
      y0 = __builtin_amdgcn_mfma_f32_16x16x32_f16(Al[B_][0][1], Bb[lt_][1], y0, 0, 0, 0); \
      y1 = __builtin_amdgcn_mfma_f32_16x16x32_f16(Ah[B_][1][0], Bb[lt_][0], y1, 0, 0, 0); \
      y1 = __builtin_amdgcn_mfma_f32_16x16x32_f16(Ah[B_][1][1], Bb[lt_][1], y1, 0, 0, 0); \
      y1 = __builtin_amdgcn_mfma_f32_16x16x32_f16(Al[B_][1][0], Bb[lt_][0], y1, 0, 0, 0); \
      y1 = __builtin_amdgcn_mfma_f32_16x16x32_f16(Al[B_][1][1], Bb[lt_][1], y1, 0, 0, 0); \
      union { fp16x2 h; unsigned u; } p0_, p1_, p2_, p3_;                            \
      p0_.h = __builtin_amdgcn_cvt_pkrtz(__expf(y0[0] + cc[B_][0].x), __expf(y0[1] + cc[B_][0].y)); \
      p1_.h = __builtin_amdgcn_cvt_pkrtz(__expf(y0[2] + cc[B_][0].z), __expf(y0[3] + cc[B_][0].w)); \
      p2_.h = __builtin_amdgcn_cvt_pkrtz(__expf(y1[0] + cc[B_][1].x), __expf(y1[1] + cc[B_][1].y)); \
      p3_.h = __builtin_amdgcn_cvt_pkrtz(__expf(y1[2] + cc[B_][1].z), __expf(y1[3] + cc[B_][1].w)); \
      union { unsigned u4[4]; half8 h8; } pa_;                                       \
      pa_.u4[0] = p0_.u; pa_.u4[1] = p1_.u; pa_.u4[2] = p2_.u; pa_.u4[3] = p3_.u;    \
      _Pragma("unroll")                                                              \
      for (int dt_ = 0; dt_ < 4; ++dt_)                                              \
        accv[lt_][dt_] = __builtin_amdgcn_mfma_f32_16x16x32_f16(pa_.h8, Vh[dt_], accv[lt_][dt_], 0, 0, 0); \
    }                                                                                \
  } while (0)

__launch_bounds__(256, 2)
__global__ void k4_out(const unsigned short* __restrict__ Ch, const unsigned short* __restrict__ Cl,
                       const float* __restrict__ c0z, const unsigned short* __restrict__ Bf,
                       const unsigned short* __restrict__ Vf, float* __restrict__ out) {
  __shared__ float Ld[2][64 * 65];
  int tid = threadIdx.x;
  int w = tid >> 6, lane = tid & 63, qd = lane >> 4, n = lane & 15;
  int bid = blockIdx.x;
  // XCD colocation: 2 bh per XCD -> Ch/Cl/Vf working set ~2.6 MB fits 4 MB L2.
  int xcd = bid & 7, idx = bid >> 3;
  int bh = (xcd << 1) | (idx >> 5), lb = idx & 31;
  int b = bh >> 3, h = bh & 7;
  int l0 = lb * 64;
  half8 Bb[4][2];
#pragma unroll
  for (int lt = 0; lt < 4; ++lt)
#pragma unroll
    for (int ksp = 0; ksp < 2; ++ksp) {
      size_t bo = ((size_t)((lb * 4 + lt) * 2 + ksp) * 64 + lane) * 8;
      Bb[lt][ksp] = *(const half8*)(Bf + bo);
    }
  floatx4 accv[4][4];
#pragma unroll
  for (int lt = 0; lt < 4; ++lt)
#pragma unroll
    for (int dt = 0; dt < 4; ++dt) accv[lt][dt] = (floatx4){0.f, 0.f, 0.f, 0.f};
  half8 Ah[2][2][2], Al[2][2][2], Vh[4];
  float4 cc[2][2];
  NLOADA(0, 0);
  // ROLLED main loop: 2 steps per iteration (compile-time dbuf slots 0/1).
#pragma clang loop unroll(disable)
  for (int it2 = 0; it2 < 8; ++it2) {
    NLOADV(it2 * 2);
    NLOADA(it2 * 2 + 1, 1);
    NCOMP(0);
    NLOADV(it2 * 2 + 1);
    if (it2 < 7) NLOADA(it2 * 2 + 2, 0);
    NCOMP(1);
  }
  // ---- cross-wave s-reduction (2 barriers total) ----
  if (w & 1) {   // waves 1,3 -> planes 0,1
    int p = w >> 1;
#pragma unroll
    for (int lt = 0; lt < 4; ++lt)
#pragma unroll
      for (int dt = 0; dt < 4; ++dt)
#pragma unroll
        for (int r = 0; r < 4; ++r)
          Ld[p][(lt * 16 + qd * 4 + r) * 65 + dt * 16 + n] = accv[lt][dt][r];
  }
  __syncthreads();
  if (!(w & 1)) {  // waves 0,2: add partner plane, write summed half
    int p = w >> 1;
#pragma unroll
    for (int lt = 0; lt < 4; ++lt)
#pragma unroll
      for (int dt = 0; dt < 4; ++dt)
#pragma unroll
        for (int r = 0; r < 4; ++r) {
          int off = (lt * 16 + qd * 4 + r) * 65 + dt * 16 + n;
          Ld[p][off] += accv[lt][dt][r];
        }
  }
  __syncthreads();
  // cooperative coalesced store: thread (dd, to) -> row d=dd, l-range to*16..+15
  int to = tid & 3, dd = tid >> 2;
  size_t ob = ((size_t)((b * 64 + dd) * 8 + h)) * 2048 + l0 + to * 16;
#pragma unroll
  for (int jq = 0; jq < 4; ++jq) {
    int t0 = to * 16 + jq * 4;
    float4 o4;
    o4.x = Ld[0][(t0 + 0) * 65 + dd] + Ld[1][(t0 + 0) * 65 + dd];
    o4.y = Ld[0][(t0 + 1) * 65 + dd] + Ld[1][(t0 + 1) * 65 + dd];
    o4.z = Ld[0][(t0 + 2) * 65 + dd] + Ld[1][(t0 + 2) * 65 + dd];
    o4.w = Ld[0][(t0 + 3) * 65 + dd] + Ld[1][(t0 + 3) * 65 + dd];
    *(float4*)(out + ob + jq * 4) = o4;
  }
}

extern "C" void kernel_launch(void* const* d_in, const int* in_sizes, int n_in,
                              void* d_out, int out_size, void* d_ws, size_t ws_size,
                              hipStream_t stream) {
  const float* q = (const float*)d_in[0];
  const float* k = (const float*)d_in[1];
  const float* v = (const float*)d_in[2];
  float* out = (float*)d_out;
  float* ws = (float*)d_ws;
  float* c0s = ws + F_C0S;
  float* c0z = ws + F_C0Z;
  unsigned short* ubase = (unsigned short*)(ws + F_END);
  unsigned short* Ch = ubase + U_CH;
  unsigned short* Cl = ubase + U_CL;
  unsigned short* Bf = ubase + U_BF;
  unsigned short* Vf = ubase + U_VF;

  mega1<<<dim3(1088), dim3(256), 0, stream>>>(q, k, v, Bf, Vf, Ch, Cl, c0s);
  k3_z<<<dim3(512), dim3(512), 0, stream>>>(Ch, Cl, c0s, Bf, c0z);
  k4_out<<<dim3(512), dim3(256), 0, stream>>>(Ch, Cl, c0z, Bf, Vf, out);
}